// Round 1
// baseline (445.645 us; speedup 1.0000x reference)
//
#include <hip/hip_runtime.h>

typedef __attribute__((ext_vector_type(4))) float f32x4;
typedef __attribute__((ext_vector_type(8))) short s16x8;

static __device__ __forceinline__ ushort f2b(float f) {
  union { float f; unsigned u; } v; v.f = f;
  unsigned u = v.u;
  unsigned r = (u + 0x7fffu + ((u >> 16) & 1u)) >> 16;
  return (ushort)r;
}
static __device__ __forceinline__ float b2f(ushort h) {
  union { unsigned u; float f; } v; v.u = ((unsigned)h) << 16;
  return v.f;
}

// ---------------- fp32 -> bf16 conversion ----------------
__global__ __launch_bounds__(256) void cvt_k(const float* __restrict__ in,
                                             ushort* __restrict__ out, int n) {
  int i = (blockIdx.x * 256 + threadIdx.x) * 4;
  if (i + 4 <= n) {
    float4 v4 = *(const float4*)(in + i);
    ushort4 o4; o4.x = f2b(v4.x); o4.y = f2b(v4.y); o4.z = f2b(v4.z); o4.w = f2b(v4.w);
    *(ushort4*)(out + i) = o4;
  } else {
    for (; i < n; ++i) out[i] = f2b(in[i]);
  }
}

// ---------------- row softmax of shortest_path, scaled by 0.5 ----------------
__global__ __launch_bounds__(256) void spsm_k(const float* __restrict__ sp,
                                              float* __restrict__ out) {
  const int Lc = 2048;
  int row = blockIdx.x;
  int tid = threadIdx.x;
  const float* r = sp + (size_t)row * Lc;
  float v[8];
  float mx = -1e30f;
#pragma unroll
  for (int j = 0; j < 8; ++j) { v[j] = r[tid + j * 256]; mx = fmaxf(mx, v[j]); }
#pragma unroll
  for (int m = 1; m < 64; m <<= 1) mx = fmaxf(mx, __shfl_xor(mx, m));
  __shared__ float redm[4], reds[4];
  if ((tid & 63) == 0) redm[tid >> 6] = mx;
  __syncthreads();
  mx = fmaxf(fmaxf(redm[0], redm[1]), fmaxf(redm[2], redm[3]));
  float s = 0.f;
#pragma unroll
  for (int j = 0; j < 8; ++j) { v[j] = __expf(v[j] - mx); s += v[j]; }
#pragma unroll
  for (int m = 1; m < 64; m <<= 1) s += __shfl_xor(s, m);
  if ((tid & 63) == 0) reds[tid >> 6] = s;
  __syncthreads();
  s = reds[0] + reds[1] + reds[2] + reds[3];
  float inv = 0.5f / s;
  float* o = out + (size_t)row * Lc;
#pragma unroll
  for (int j = 0; j < 8; ++j) o[tid + j * 256] = v[j] * inv;
}

// ---------------- generic bf16 GEMM: C[M,N] = act(A[M,K] * W[N,K]^T + bias) ----------------
__global__ __launch_bounds__(256, 2) void gemm_k(
    const ushort* __restrict__ A, const ushort* __restrict__ W,
    const float* __restrict__ bias, ushort* __restrict__ C,
    int M, int N, int K, int relu) {
  __shared__ ushort As[128][72];
  __shared__ ushort Bs[128][72];
  const int tid = threadIdx.x;
  const int lane = tid & 63;
  const int wave = tid >> 6;
  const int wm = (wave >> 1) * 64;
  const int wn = (wave & 1) * 64;
  const int bm = blockIdx.x * 128;
  const int bn = blockIdx.y * 128;
  const int srow = tid >> 3;
  const int scol = (tid & 7) * 8;

  f32x4 acc[4][4];
#pragma unroll
  for (int i = 0; i < 4; ++i)
#pragma unroll
    for (int j = 0; j < 4; ++j) acc[i][j] = (f32x4){0.f, 0.f, 0.f, 0.f};

  for (int k0 = 0; k0 < K; k0 += 64) {
#pragma unroll
    for (int p = 0; p < 4; ++p) {
      int r = srow + p * 32;
      *(uint4*)&As[r][scol] = *(const uint4*)(A + (size_t)(bm + r) * K + k0 + scol);
      *(uint4*)&Bs[r][scol] = *(const uint4*)(W + (size_t)(bn + r) * K + k0 + scol);
    }
    __syncthreads();
    const int kb = 8 * (lane >> 4);
#pragma unroll
    for (int kk = 0; kk < 64; kk += 32) {
      s16x8 af[4], bf[4];
#pragma unroll
      for (int t = 0; t < 4; ++t) {
        af[t] = *(const s16x8*)&As[wm + t * 16 + (lane & 15)][kk + kb];
        bf[t] = *(const s16x8*)&Bs[wn + t * 16 + (lane & 15)][kk + kb];
      }
#pragma unroll
      for (int mt = 0; mt < 4; ++mt)
#pragma unroll
        for (int nt = 0; nt < 4; ++nt)
          acc[mt][nt] = __builtin_amdgcn_mfma_f32_16x16x32_bf16(af[mt], bf[nt], acc[mt][nt], 0, 0, 0);
    }
    __syncthreads();
  }

  const int rg = lane >> 4, cl = lane & 15;
#pragma unroll
  for (int nt = 0; nt < 4; ++nt) {
    int c = bn + wn + nt * 16 + cl;
    float bv = bias[c];
#pragma unroll
    for (int mt = 0; mt < 4; ++mt) {
#pragma unroll
      for (int i = 0; i < 4; ++i) {
        int r = bm + wm + mt * 16 + rg * 4 + i;
        float v = acc[mt][nt][i] + bv;
        if (relu) v = fmaxf(v, 0.f);
        C[(size_t)r * N + c] = f2b(v);
      }
    }
  }
}

// ---------------- flash attention with additive bias ----------------
__global__ __launch_bounds__(256, 2) void attn_k(
    const ushort* __restrict__ q, const ushort* __restrict__ k,
    const ushort* __restrict__ v, const float* __restrict__ bias,
    ushort* __restrict__ o) {
  const int Lc = 2048, STR = 1024;
  int h = blockIdx.x;
  int m0 = blockIdx.y * 64;
  int tid = threadIdx.x, lane = tid & 63, wave = tid >> 6;

  __shared__ ushort Qs[64][72];
  __shared__ ushort Ks[64][72];
  __shared__ ushort Vt[64][72];
  __shared__ ushort Ps[4][16][72];
  __shared__ float Bs[64][64];

  int srow = tid >> 3, scol = (tid & 7) * 8;
#pragma unroll
  for (int p = 0; p < 2; ++p) {
    int r = srow + p * 32;
    *(uint4*)&Qs[r][scol] = *(const uint4*)(q + (size_t)(m0 + r) * STR + h * 64 + scol);
  }

  f32x4 oacc[4];
#pragma unroll
  for (int i = 0; i < 4; ++i) oacc[i] = (f32x4){0.f, 0.f, 0.f, 0.f};
  float mstate[4] = {-1e30f, -1e30f, -1e30f, -1e30f};
  float lstate[4] = {0.f, 0.f, 0.f, 0.f};

  const int rg = lane >> 4, cl = lane & 15;
  const int kb = 8 * rg;
  int brow = tid >> 2, bcol = (tid & 3) * 16;

  for (int n0 = 0; n0 < Lc; n0 += 64) {
    __syncthreads();
#pragma unroll
    for (int p = 0; p < 2; ++p) {
      int r = srow + p * 32;
      *(uint4*)&Ks[r][scol] = *(const uint4*)(k + (size_t)(n0 + r) * STR + h * 64 + scol);
      uint4 dv = *(const uint4*)(v + (size_t)(n0 + r) * STR + h * 64 + scol);
      const ushort* pv = (const ushort*)&dv;
#pragma unroll
      for (int j = 0; j < 8; ++j) Vt[scol + j][r] = pv[j];
    }
#pragma unroll
    for (int j = 0; j < 4; ++j)
      *(float4*)&Bs[brow][bcol + j * 4] =
          *(const float4*)(bias + (size_t)(m0 + brow) * Lc + n0 + bcol + j * 4);
    __syncthreads();

    f32x4 sacc[4];
#pragma unroll
    for (int i = 0; i < 4; ++i) sacc[i] = (f32x4){0.f, 0.f, 0.f, 0.f};
#pragma unroll
    for (int kk = 0; kk < 64; kk += 32) {
      s16x8 a = *(const s16x8*)&Qs[wave * 16 + cl][kk + kb];
#pragma unroll
      for (int nt = 0; nt < 4; ++nt) {
        s16x8 b = *(const s16x8*)&Ks[nt * 16 + cl][kk + kb];
        sacc[nt] = __builtin_amdgcn_mfma_f32_16x16x32_bf16(a, b, sacc[nt], 0, 0, 0);
      }
    }
#pragma unroll
    for (int i = 0; i < 4; ++i) {
      int qr = wave * 16 + rg * 4 + i;
      float mx = -1e30f;
#pragma unroll
      for (int nt = 0; nt < 4; ++nt) {
        float sv = sacc[nt][i] * 0.125f + Bs[qr][nt * 16 + cl];
        sacc[nt][i] = sv;
        mx = fmaxf(mx, sv);
      }
#pragma unroll
      for (int m = 1; m < 16; m <<= 1) mx = fmaxf(mx, __shfl_xor(mx, m));
      float mnew = fmaxf(mstate[i], mx);
      float alpha = __expf(mstate[i] - mnew);
      mstate[i] = mnew;
      float rs = 0.f;
#pragma unroll
      for (int nt = 0; nt < 4; ++nt) {
        float p = __expf(sacc[nt][i] - mnew);
        sacc[nt][i] = p;
        rs += p;
      }
#pragma unroll
      for (int m = 1; m < 16; m <<= 1) rs += __shfl_xor(rs, m);
      lstate[i] = lstate[i] * alpha + rs;
#pragma unroll
      for (int nt = 0; nt < 4; ++nt) oacc[nt][i] *= alpha;
    }
#pragma unroll
    for (int nt = 0; nt < 4; ++nt)
#pragma unroll
      for (int i = 0; i < 4; ++i)
        Ps[wave][rg * 4 + i][nt * 16 + cl] = f2b(sacc[nt][i]);
#pragma unroll
    for (int kk = 0; kk < 64; kk += 32) {
      s16x8 a = *(const s16x8*)&Ps[wave][cl][kk + kb];
#pragma unroll
      for (int nt = 0; nt < 4; ++nt) {
        s16x8 b = *(const s16x8*)&Vt[nt * 16 + cl][kk + kb];
        oacc[nt] = __builtin_amdgcn_mfma_f32_16x16x32_bf16(a, b, oacc[nt], 0, 0, 0);
      }
    }
  }
#pragma unroll
  for (int nt = 0; nt < 4; ++nt) {
#pragma unroll
    for (int i = 0; i < 4; ++i) {
      int r = m0 + wave * 16 + rg * 4 + i;
      int c = h * 64 + nt * 16 + cl;
      o[(size_t)r * STR + c] = f2b(oacc[nt][i] / lstate[i]);
    }
  }
}

// ---------------- residual + LayerNorm ----------------
__global__ __launch_bounds__(256) void ln_k(const float* __restrict__ base,
                                            const ushort* __restrict__ add,
                                            const float* __restrict__ g,
                                            const float* __restrict__ be,
                                            ushort* __restrict__ outb,
                                            float* __restrict__ outf) {
  const int Dc = 1024;
  int row = blockIdx.x;
  int tid = threadIdx.x;
  const float* br = base + (size_t)row * Dc + tid * 4;
  const ushort* ar = add + (size_t)row * Dc + tid * 4;
  float4 bx = *(const float4*)br;
  ushort4 ax = *(const ushort4*)ar;
  float v0 = bx.x + b2f(ax.x), v1 = bx.y + b2f(ax.y);
  float v2 = bx.z + b2f(ax.z), v3 = bx.w + b2f(ax.w);
  float s = v0 + v1 + v2 + v3;
  __shared__ float red[4];
#pragma unroll
  for (int m = 1; m < 64; m <<= 1) s += __shfl_xor(s, m);
  if ((tid & 63) == 0) red[tid >> 6] = s;
  __syncthreads();
  s = red[0] + red[1] + red[2] + red[3];
  float mu = s * (1.f / Dc);
  float d0 = v0 - mu, d1 = v1 - mu, d2 = v2 - mu, d3 = v3 - mu;
  float ss = d0 * d0 + d1 * d1 + d2 * d2 + d3 * d3;
  __syncthreads();
#pragma unroll
  for (int m = 1; m < 64; m <<= 1) ss += __shfl_xor(ss, m);
  if ((tid & 63) == 0) red[tid >> 6] = ss;
  __syncthreads();
  ss = red[0] + red[1] + red[2] + red[3];
  float rs = rsqrtf(ss * (1.f / Dc) + 1e-5f);
  int c = tid * 4;
  float4 gv = *(const float4*)(g + c);
  float4 bev = *(const float4*)(be + c);
  float y0 = d0 * rs * gv.x + bev.x;
  float y1 = d1 * rs * gv.y + bev.y;
  float y2 = d2 * rs * gv.z + bev.z;
  float y3 = d3 * rs * gv.w + bev.w;
  size_t o = (size_t)row * Dc + c;
  if (outb) {
    ushort4 ob4; ob4.x = f2b(y0); ob4.y = f2b(y1); ob4.z = f2b(y2); ob4.w = f2b(y3);
    *(ushort4*)(outb + o) = ob4;
  }
  if (outf) {
    float4 of4; of4.x = y0; of4.y = y1; of4.z = y2; of4.w = y3;
    *(float4*)(outf + o) = of4;
  }
}

extern "C" void kernel_launch(void* const* d_in, const int* in_sizes, int n_in,
                              void* d_out, int out_size, void* d_ws, size_t ws_size,
                              hipStream_t stream) {
  const int L = 2048, D = 1024, H = 16, KS = 1024, VS = 1024, HID = 4096;
  const float* x   = (const float*)d_in[0];
  const float* sp  = (const float*)d_in[1];
  const float* Wq  = (const float*)d_in[2];  const float* bq  = (const float*)d_in[3];
  const float* Wk  = (const float*)d_in[4];  const float* bk  = (const float*)d_in[5];
  const float* Wv  = (const float*)d_in[6];  const float* bv  = (const float*)d_in[7];
  const float* Wqp = (const float*)d_in[8];  const float* bqp = (const float*)d_in[9];
  const float* Wkp = (const float*)d_in[10]; const float* bkp = (const float*)d_in[11];
  const float* Wvp = (const float*)d_in[12]; const float* bvp = (const float*)d_in[13];
  const float* Wo  = (const float*)d_in[14]; const float* bo  = (const float*)d_in[15];
  const float* W1  = (const float*)d_in[16]; const float* b1  = (const float*)d_in[17];
  const float* W2  = (const float*)d_in[18]; const float* b2  = (const float*)d_in[19];
  const float* g1  = (const float*)d_in[20]; const float* be1 = (const float*)d_in[21];
  const float* g2  = (const float*)d_in[22]; const float* be2 = (const float*)d_in[23];
  float* out = (float*)d_out;

  size_t off = 0;
  char* base = (char*)d_ws;
  auto alloc = [&](size_t b) {
    char* p = base + off;
    off += (b + 255) & ~(size_t)255;
    return p;
  };
  ushort* xb   = (ushort*)alloc((size_t)L * D * 2);
  ushort* wqb  = (ushort*)alloc((size_t)KS * D * 2);
  ushort* wkb  = (ushort*)alloc((size_t)KS * D * 2);
  ushort* wvb  = (ushort*)alloc((size_t)VS * D * 2);
  ushort* wqpb = (ushort*)alloc((size_t)KS * KS * 2);
  ushort* wkpb = (ushort*)alloc((size_t)KS * KS * 2);
  ushort* wvpb = (ushort*)alloc((size_t)VS * VS * 2);
  ushort* wob  = (ushort*)alloc((size_t)D * VS * 2);
  ushort* w1b  = (ushort*)alloc((size_t)HID * D * 2);
  ushort* w2b  = (ushort*)alloc((size_t)D * HID * 2);
  ushort* q1   = (ushort*)alloc((size_t)L * KS * 2);
  ushort* k1   = (ushort*)alloc((size_t)L * KS * 2);
  ushort* v1   = (ushort*)alloc((size_t)L * VS * 2);
  ushort* qf   = (ushort*)alloc((size_t)L * KS * 2);
  ushort* kf   = (ushort*)alloc((size_t)L * KS * 2);
  ushort* vf   = (ushort*)alloc((size_t)L * VS * 2);
  float*  sps  = (float*)alloc((size_t)L * L * 4);
  ushort* ob   = (ushort*)alloc((size_t)L * VS * 2);
  ushort* hb   = (ushort*)alloc((size_t)L * D * 2);
  float*  hf   = (float*)alloc((size_t)L * D * 4);
  ushort* ffn1 = (ushort*)sps;  // reuse: sps dead after attention; same 16 MB
  ushort* opb  = q1;            // reuse: q1 dead after qf
  ushort* fb   = k1;            // reuse: k1 dead after kf

  auto cvt = [&](const float* s, ushort* dst, size_t n) {
    cvt_k<<<dim3((unsigned)((n / 4 + 255) / 256)), dim3(256), 0, stream>>>(s, dst, (int)n);
  };
  cvt(x, xb, (size_t)L * D);
  cvt(Wq, wqb, (size_t)KS * D);
  cvt(Wk, wkb, (size_t)KS * D);
  cvt(Wv, wvb, (size_t)VS * D);
  cvt(Wqp, wqpb, (size_t)KS * KS);
  cvt(Wkp, wkpb, (size_t)KS * KS);
  cvt(Wvp, wvpb, (size_t)VS * VS);
  cvt(Wo, wob, (size_t)D * VS);
  cvt(W1, w1b, (size_t)HID * D);
  cvt(W2, w2b, (size_t)D * HID);

  spsm_k<<<dim3(L), dim3(256), 0, stream>>>(sp, sps);

  gemm_k<<<dim3(L / 128, KS / 128), dim3(256), 0, stream>>>(xb, wqb, bq, q1, L, KS, D, 0);
  gemm_k<<<dim3(L / 128, KS / 128), dim3(256), 0, stream>>>(xb, wkb, bk, k1, L, KS, D, 0);
  gemm_k<<<dim3(L / 128, VS / 128), dim3(256), 0, stream>>>(xb, wvb, bv, v1, L, VS, D, 0);
  gemm_k<<<dim3(L / 128, KS / 128), dim3(256), 0, stream>>>(q1, wqpb, bqp, qf, L, KS, KS, 0);
  gemm_k<<<dim3(L / 128, KS / 128), dim3(256), 0, stream>>>(k1, wkpb, bkp, kf, L, KS, KS, 0);
  gemm_k<<<dim3(L / 128, VS / 128), dim3(256), 0, stream>>>(v1, wvpb, bvp, vf, L, VS, VS, 0);

  attn_k<<<dim3(H, L / 64), dim3(256), 0, stream>>>(qf, kf, vf, sps, ob);

  gemm_k<<<dim3(L / 128, D / 128), dim3(256), 0, stream>>>(ob, wob, bo, opb, L, D, VS, 0);
  ln_k<<<dim3(L), dim3(256), 0, stream>>>(x, opb, g1, be1, hb, hf);
  gemm_k<<<dim3(L / 128, HID / 128), dim3(256), 0, stream>>>(hb, w1b, b1, ffn1, L, HID, D, 1);
  gemm_k<<<dim3(L / 128, D / 128), dim3(256), 0, stream>>>(ffn1, w2b, b2, fb, L, D, HID, 1);
  ln_k<<<dim3(L), dim3(256), 0, stream>>>(hf, fb, g2, be2, (ushort*)nullptr, out);
}

// Round 2
// 342.239 us; speedup vs baseline: 1.3021x; 1.3021x over previous
//
#include <hip/hip_runtime.h>

typedef __attribute__((ext_vector_type(4))) float f32x4;
typedef __attribute__((ext_vector_type(8))) short s16x8;

static __device__ __forceinline__ ushort f2b(float f) {
  union { float f; unsigned u; } v; v.f = f;
  unsigned u = v.u;
  unsigned r = (u + 0x7fffu + ((u >> 16) & 1u)) >> 16;
  return (ushort)r;
}
static __device__ __forceinline__ float b2f(ushort h) {
  union { unsigned u; float f; } v; v.u = ((unsigned)h) << 16;
  return v.f;
}

static __device__ __forceinline__ void gload_lds16(const ushort* g, ushort* l) {
  __builtin_amdgcn_global_load_lds(
      (const __attribute__((address_space(1))) void*)g,
      (__attribute__((address_space(3))) void*)l, 16, 0, 0);
}

// ---------------- fp32 -> bf16 conversion ----------------
__global__ __launch_bounds__(256) void cvt_k(const float* __restrict__ in,
                                             ushort* __restrict__ out, int n) {
  int i = (blockIdx.x * 256 + threadIdx.x) * 4;
  if (i + 4 <= n) {
    float4 v4 = *(const float4*)(in + i);
    ushort4 o4; o4.x = f2b(v4.x); o4.y = f2b(v4.y); o4.z = f2b(v4.z); o4.w = f2b(v4.w);
    *(ushort4*)(out + i) = o4;
  } else {
    for (; i < n; ++i) out[i] = f2b(in[i]);
  }
}

// ---------------- row softmax of shortest_path, scaled by 0.5 ----------------
__global__ __launch_bounds__(256) void spsm_k(const float* __restrict__ sp,
                                              float* __restrict__ out) {
  const int Lc = 2048;
  int row = blockIdx.x;
  int tid = threadIdx.x;
  const float* r = sp + (size_t)row * Lc;
  float v[8];
  float mx = -1e30f;
#pragma unroll
  for (int j = 0; j < 8; ++j) { v[j] = r[tid + j * 256]; mx = fmaxf(mx, v[j]); }
#pragma unroll
  for (int m = 1; m < 64; m <<= 1) mx = fmaxf(mx, __shfl_xor(mx, m));
  __shared__ float redm[4], reds[4];
  if ((tid & 63) == 0) redm[tid >> 6] = mx;
  __syncthreads();
  mx = fmaxf(fmaxf(redm[0], redm[1]), fmaxf(redm[2], redm[3]));
  float s = 0.f;
#pragma unroll
  for (int j = 0; j < 8; ++j) { v[j] = __expf(v[j] - mx); s += v[j]; }
#pragma unroll
  for (int m = 1; m < 64; m <<= 1) s += __shfl_xor(s, m);
  if ((tid & 63) == 0) reds[tid >> 6] = s;
  __syncthreads();
  s = reds[0] + reds[1] + reds[2] + reds[3];
  float inv = 0.5f / s;
  float* o = out + (size_t)row * Lc;
#pragma unroll
  for (int j = 0; j < 8; ++j) o[tid + j * 256] = v[j] * inv;
}

// ---------------- V pre-transpose: vf[L][1024] -> vT[16][64][2048] ----------------
__global__ __launch_bounds__(256) void vtr_k(const ushort* __restrict__ vf,
                                             ushort* __restrict__ vT) {
  __shared__ ushort t[64][72];
  int tid = threadIdx.x;
  int r = tid >> 3, c8 = (tid & 7) * 8;
  int l0 = blockIdx.x * 64, h = blockIdx.y;
#pragma unroll
  for (int p = 0; p < 2; ++p)
    *(uint4*)&t[r + p * 32][c8] =
        *(const uint4*)(vf + (size_t)(l0 + r + p * 32) * 1024 + h * 64 + c8);
  __syncthreads();
#pragma unroll
  for (int p = 0; p < 2; ++p) {
    int d = r + p * 32;
    ushort tmp[8];
#pragma unroll
    for (int j = 0; j < 8; ++j) tmp[j] = t[c8 + j][d];
    *(uint4*)(vT + ((size_t)h * 64 + d) * 2048 + l0 + c8) = *(uint4*)tmp;
  }
}

// ---------------- bf16 GEMM (m97 structure): C = act((A * W^T + bias) * oscale) ----------------
template <int BM>
__global__ __launch_bounds__(256, 2) void gemm_k(
    const ushort* __restrict__ A, const ushort* __restrict__ W,
    const float* __restrict__ bias, ushort* __restrict__ C,
    int M, int N, int K, int relu, float oscale) {
  constexpr int MT = BM / 32;  // 16-row m-frags per wave
  __shared__ ushort As[BM][64];
  __shared__ ushort Bs[128][64];
  const int tid = threadIdx.x;
  const int lane = tid & 63;
  const int wave = tid >> 6;
  const int wm = (wave >> 1) * (BM / 2);
  const int wn = (wave & 1) * 64;
  const int bm = blockIdx.x * BM;
  const int bn = blockIdx.y * 128;
  const int cl = lane & 15, rg = lane >> 4;
  const int lrow = lane >> 3, lcol = (lane & 7) * 8;

  f32x4 acc[MT][4];
#pragma unroll
  for (int i = 0; i < MT; ++i)
#pragma unroll
    for (int j = 0; j < 4; ++j) acc[i][j] = (f32x4){0.f, 0.f, 0.f, 0.f};

  const ushort* gA = A + (size_t)(bm + wave * 8 + lrow) * K + lcol;
  const ushort* gB = W + (size_t)(bn + wave * 8 + lrow) * K + lcol;
  ushort* lA = &As[wave * 8][0];
  ushort* lB = &Bs[wave * 8][0];

  for (int k0 = 0; k0 < K; k0 += 64) {
#pragma unroll
    for (int c = 0; c < MT; ++c)
      gload_lds16(gA + (size_t)(c * 32) * K + k0, lA + c * 2048);
#pragma unroll
    for (int c = 0; c < 4; ++c)
      gload_lds16(gB + (size_t)(c * 32) * K + k0, lB + c * 2048);
    __syncthreads();
    const int kb = 8 * rg;
#pragma unroll
    for (int kk = 0; kk < 64; kk += 32) {
      s16x8 af[MT], bf[4];
#pragma unroll
      for (int mt = 0; mt < MT; ++mt)
        af[mt] = *(const s16x8*)&As[wm + mt * 16 + cl][kk + kb];
#pragma unroll
      for (int nt = 0; nt < 4; ++nt)
        bf[nt] = *(const s16x8*)&Bs[wn + nt * 16 + cl][kk + kb];
#pragma unroll
      for (int mt = 0; mt < MT; ++mt)
#pragma unroll
        for (int nt = 0; nt < 4; ++nt)
          acc[mt][nt] = __builtin_amdgcn_mfma_f32_16x16x32_bf16(af[mt], bf[nt], acc[mt][nt], 0, 0, 0);
    }
    __syncthreads();
  }

#pragma unroll
  for (int nt = 0; nt < 4; ++nt) {
    int c = bn + wn + nt * 16 + cl;
    float bv = bias[c];
#pragma unroll
    for (int mt = 0; mt < MT; ++mt) {
#pragma unroll
      for (int i = 0; i < 4; ++i) {
        int r = bm + wm + mt * 16 + rg * 4 + i;
        float v = (acc[mt][nt][i] + bv) * oscale;
        if (relu) v = fmaxf(v, 0.f);
        C[(size_t)r * N + c] = f2b(v);
      }
    }
  }
}

// ---------------- flash attention, KV-split, bias-seeded accumulator ----------------
__global__ __launch_bounds__(256, 2) void attn_k(
    const ushort* __restrict__ q, const ushort* __restrict__ k,
    const ushort* __restrict__ vT, const float* __restrict__ bias,
    ushort* __restrict__ opart, float* __restrict__ ml) {
  const int Lc = 2048, STR = 1024;
  int h = blockIdx.x;
  int m0 = blockIdx.y * 64;
  int s = blockIdx.z;
  int nb = s * 1024, ne = nb + 1024;
  int tid = threadIdx.x, lane = tid & 63, wave = tid >> 6;

  __shared__ ushort Qs[64][72];
  __shared__ ushort Ks[64][72];
  __shared__ ushort Vs[64][72];
  __shared__ ushort Ps[4][16][72];

  int srow = tid >> 3, scol = (tid & 7) * 8;
#pragma unroll
  for (int p = 0; p < 2; ++p) {
    int r = srow + p * 32;
    *(uint4*)&Qs[r][scol] = *(const uint4*)(q + (size_t)(m0 + r) * STR + h * 64 + scol);
  }

  f32x4 oacc[4];
#pragma unroll
  for (int i = 0; i < 4; ++i) oacc[i] = (f32x4){0.f, 0.f, 0.f, 0.f};
  float mstate[4] = {-1e30f, -1e30f, -1e30f, -1e30f};
  float lstate[4] = {0.f, 0.f, 0.f, 0.f};

  const int rg = lane >> 4, cl = lane & 15;
  const int kb = 8 * rg;

  for (int n0 = nb; n0 < ne; n0 += 64) {
    __syncthreads();
#pragma unroll
    for (int p = 0; p < 2; ++p) {
      int r = srow + p * 32;
      *(uint4*)&Ks[r][scol] = *(const uint4*)(k + (size_t)(n0 + r) * STR + h * 64 + scol);
      *(uint4*)&Vs[r][scol] = *(const uint4*)(vT + ((size_t)h * 64 + r) * 2048 + n0 + scol);
    }
    __syncthreads();

    // seed scores with the softmax(sp)*0.5 bias (q already carries the 1/8 scale)
    f32x4 sacc[4];
#pragma unroll
    for (int nt = 0; nt < 4; ++nt)
#pragma unroll
      for (int i = 0; i < 4; ++i)
        sacc[nt][i] = bias[(size_t)(m0 + wave * 16 + rg * 4 + i) * Lc + n0 + nt * 16 + cl];

#pragma unroll
    for (int kk = 0; kk < 64; kk += 32) {
      s16x8 a = *(const s16x8*)&Qs[wave * 16 + cl][kk + kb];
#pragma unroll
      for (int nt = 0; nt < 4; ++nt) {
        s16x8 b = *(const s16x8*)&Ks[nt * 16 + cl][kk + kb];
        sacc[nt] = __builtin_amdgcn_mfma_f32_16x16x32_bf16(a, b, sacc[nt], 0, 0, 0);
      }
    }
#pragma unroll
    for (int i = 0; i < 4; ++i) {
      float mx = -1e30f;
#pragma unroll
      for (int nt = 0; nt < 4; ++nt) mx = fmaxf(mx, sacc[nt][i]);
#pragma unroll
      for (int m = 1; m < 16; m <<= 1) mx = fmaxf(mx, __shfl_xor(mx, m));
      float mnew = fmaxf(mstate[i], mx);
      float alpha = __expf(mstate[i] - mnew);
      mstate[i] = mnew;
      float rs = 0.f;
#pragma unroll
      for (int nt = 0; nt < 4; ++nt) {
        float p = __expf(sacc[nt][i] - mnew);
        sacc[nt][i] = p;
        rs += p;
      }
#pragma unroll
      for (int m = 1; m < 16; m <<= 1) rs += __shfl_xor(rs, m);
      lstate[i] = lstate[i] * alpha + rs;
#pragma unroll
      for (int nt = 0; nt < 4; ++nt) oacc[nt][i] *= alpha;
    }
#pragma unroll
    for (int nt = 0; nt < 4; ++nt)
#pragma unroll
      for (int i = 0; i < 4; ++i)
        Ps[wave][rg * 4 + i][nt * 16 + cl] = f2b(sacc[nt][i]);
#pragma unroll
    for (int kk = 0; kk < 64; kk += 32) {
      s16x8 a = *(const s16x8*)&Ps[wave][cl][kk + kb];
#pragma unroll
      for (int nt = 0; nt < 4; ++nt) {
        s16x8 b = *(const s16x8*)&Vs[nt * 16 + cl][kk + kb];
        oacc[nt] = __builtin_amdgcn_mfma_f32_16x16x32_bf16(a, b, oacc[nt], 0, 0, 0);
      }
    }
  }
  // write unnormalized partial O (bf16) + (m,l)
#pragma unroll
  for (int nt = 0; nt < 4; ++nt) {
#pragma unroll
    for (int i = 0; i < 4; ++i) {
      int r = m0 + wave * 16 + rg * 4 + i;
      int c = h * 64 + nt * 16 + cl;
      opart[((size_t)s * Lc + r) * STR + c] = f2b(oacc[nt][i]);
    }
  }
  if (cl == 0) {
#pragma unroll
    for (int i = 0; i < 4; ++i) {
      int r = m0 + wave * 16 + rg * 4 + i;
      float2 t; t.x = mstate[i]; t.y = lstate[i];
      *(float2*)(ml + ((size_t)(s * 16 + h) * Lc + r) * 2) = t;
    }
  }
}

// ---------------- combine the 2 KV-splits ----------------
__global__ __launch_bounds__(256) void acomb_k(const ushort* __restrict__ op,
                                               const float* __restrict__ ml,
                                               ushort* __restrict__ ob) {
  const int Lc = 2048, STR = 1024;
  int qrow = blockIdx.x;
  int tid = threadIdx.x;
  int c = tid * 4;
  int h = c >> 6;
  const float* p0 = ml + ((size_t)h * Lc + qrow) * 2;
  const float* p1 = ml + ((size_t)(16 + h) * Lc + qrow) * 2;
  float m0 = p0[0], l0 = p0[1], m1 = p1[0], l1 = p1[1];
  float mm = fmaxf(m0, m1);
  float w0 = __expf(m0 - mm), w1 = __expf(m1 - mm);
  float inv = 1.f / (w0 * l0 + w1 * l1);
  w0 *= inv; w1 *= inv;
  ushort4 a = *(const ushort4*)(op + (size_t)qrow * STR + c);
  ushort4 b = *(const ushort4*)(op + ((size_t)Lc + qrow) * STR + c);
  ushort4 o;
  o.x = f2b(b2f(a.x) * w0 + b2f(b.x) * w1);
  o.y = f2b(b2f(a.y) * w0 + b2f(b.y) * w1);
  o.z = f2b(b2f(a.z) * w0 + b2f(b.z) * w1);
  o.w = f2b(b2f(a.w) * w0 + b2f(b.w) * w1);
  *(ushort4*)(ob + (size_t)qrow * STR + c) = o;
}

// ---------------- residual + LayerNorm ----------------
__global__ __launch_bounds__(256) void ln_k(const float* __restrict__ base,
                                            const ushort* __restrict__ add,
                                            const float* __restrict__ g,
                                            const float* __restrict__ be,
                                            ushort* __restrict__ outb,
                                            float* __restrict__ outf) {
  const int Dc = 1024;
  int row = blockIdx.x;
  int tid = threadIdx.x;
  const float* br = base + (size_t)row * Dc + tid * 4;
  const ushort* ar = add + (size_t)row * Dc + tid * 4;
  float4 bx = *(const float4*)br;
  ushort4 ax = *(const ushort4*)ar;
  float v0 = bx.x + b2f(ax.x), v1 = bx.y + b2f(ax.y);
  float v2 = bx.z + b2f(ax.z), v3 = bx.w + b2f(ax.w);
  float s = v0 + v1 + v2 + v3;
  __shared__ float red[4];
#pragma unroll
  for (int m = 1; m < 64; m <<= 1) s += __shfl_xor(s, m);
  if ((tid & 63) == 0) red[tid >> 6] = s;
  __syncthreads();
  s = red[0] + red[1] + red[2] + red[3];
  float mu = s * (1.f / Dc);
  float d0 = v0 - mu, d1 = v1 - mu, d2 = v2 - mu, d3 = v3 - mu;
  float ss = d0 * d0 + d1 * d1 + d2 * d2 + d3 * d3;
  __syncthreads();
#pragma unroll
  for (int m = 1; m < 64; m <<= 1) ss += __shfl_xor(ss, m);
  if ((tid & 63) == 0) red[tid >> 6] = ss;
  __syncthreads();
  ss = red[0] + red[1] + red[2] + red[3];
  float rs = rsqrtf(ss * (1.f / Dc) + 1e-5f);
  int c = tid * 4;
  float4 gv = *(const float4*)(g + c);
  float4 bev = *(const float4*)(be + c);
  float y0 = d0 * rs * gv.x + bev.x;
  float y1 = d1 * rs * gv.y + bev.y;
  float y2 = d2 * rs * gv.z + bev.z;
  float y3 = d3 * rs * gv.w + bev.w;
  size_t o = (size_t)row * Dc + c;
  if (outb) {
    ushort4 ob4; ob4.x = f2b(y0); ob4.y = f2b(y1); ob4.z = f2b(y2); ob4.w = f2b(y3);
    *(ushort4*)(outb + o) = ob4;
  }
  if (outf) {
    float4 of4; of4.x = y0; of4.y = y1; of4.z = y2; of4.w = y3;
    *(float4*)(outf + o) = of4;
  }
}

extern "C" void kernel_launch(void* const* d_in, const int* in_sizes, int n_in,
                              void* d_out, int out_size, void* d_ws, size_t ws_size,
                              hipStream_t stream) {
  const int L = 2048, D = 1024, H = 16, KS = 1024, VS = 1024, HID = 4096;
  const float* x   = (const float*)d_in[0];
  const float* sp  = (const float*)d_in[1];
  const float* Wq  = (const float*)d_in[2];  const float* bq  = (const float*)d_in[3];
  const float* Wk  = (const float*)d_in[4];  const float* bk  = (const float*)d_in[5];
  const float* Wv  = (const float*)d_in[6];  const float* bv  = (const float*)d_in[7];
  const float* Wqp = (const float*)d_in[8];  const float* bqp = (const float*)d_in[9];
  const float* Wkp = (const float*)d_in[10]; const float* bkp = (const float*)d_in[11];
  const float* Wvp = (const float*)d_in[12]; const float* bvp = (const float*)d_in[13];
  const float* Wo  = (const float*)d_in[14]; const float* bo  = (const float*)d_in[15];
  const float* W1  = (const float*)d_in[16]; const float* b1  = (const float*)d_in[17];
  const float* W2  = (const float*)d_in[18]; const float* b2  = (const float*)d_in[19];
  const float* g1  = (const float*)d_in[20]; const float* be1 = (const float*)d_in[21];
  const float* g2  = (const float*)d_in[22]; const float* be2 = (const float*)d_in[23];
  float* out = (float*)d_out;

  size_t off = 0;
  char* base = (char*)d_ws;
  auto alloc = [&](size_t b) {
    char* p = base + off;
    off += (b + 255) & ~(size_t)255;
    return p;
  };
  ushort* xb   = (ushort*)alloc((size_t)L * D * 2);
  ushort* wqb  = (ushort*)alloc((size_t)KS * D * 2);
  ushort* wkb  = (ushort*)alloc((size_t)KS * D * 2);
  ushort* wvb  = (ushort*)alloc((size_t)VS * D * 2);
  ushort* wqpb = (ushort*)alloc((size_t)KS * KS * 2);
  ushort* wkpb = (ushort*)alloc((size_t)KS * KS * 2);
  ushort* wvpb = (ushort*)alloc((size_t)VS * VS * 2);
  ushort* wob  = (ushort*)alloc((size_t)D * VS * 2);
  ushort* w1b  = (ushort*)alloc((size_t)HID * D * 2);
  ushort* w2b  = (ushort*)alloc((size_t)D * HID * 2);
  ushort* q1   = (ushort*)alloc((size_t)L * KS * 2);
  ushort* k1   = (ushort*)alloc((size_t)L * KS * 2);
  ushort* v1   = (ushort*)alloc((size_t)L * VS * 2);
  ushort* qf   = (ushort*)alloc((size_t)L * KS * 2);
  ushort* kf   = (ushort*)alloc((size_t)L * KS * 2);
  ushort* vf   = (ushort*)alloc((size_t)L * VS * 2);
  ushort* vT   = (ushort*)alloc((size_t)H * 64 * L * 2);
  float*  sps  = (float*)alloc((size_t)L * L * 4);
  ushort* ob   = (ushort*)alloc((size_t)L * VS * 2);
  ushort* hb   = (ushort*)alloc((size_t)L * D * 2);
  float*  hf   = (float*)alloc((size_t)L * D * 4);
  ushort* ffn1 = (ushort*)sps;   // reuse: sps dead after attention
  ushort* opart = q1;            // reuse: q1+k1 dead after qf/kf (2*L*1024 bf16 = 8 MB)
  float*  mlbuf = (float*)v1;    // reuse: v1 dead after vT (needs 0.5 MB)
  ushort* opb  = q1;             // reuse after combine
  ushort* fb   = k1;             // reuse after combine

  auto cvt = [&](const float* s, ushort* dst, size_t n) {
    cvt_k<<<dim3((unsigned)((n / 4 + 255) / 256)), dim3(256), 0, stream>>>(s, dst, (int)n);
  };
  cvt(x, xb, (size_t)L * D);
  cvt(Wq, wqb, (size_t)KS * D);
  cvt(Wk, wkb, (size_t)KS * D);
  cvt(Wv, wvb, (size_t)VS * D);
  cvt(Wqp, wqpb, (size_t)KS * KS);
  cvt(Wkp, wkpb, (size_t)KS * KS);
  cvt(Wvp, wvpb, (size_t)VS * VS);
  cvt(Wo, wob, (size_t)D * VS);
  cvt(W1, w1b, (size_t)HID * D);
  cvt(W2, w2b, (size_t)D * HID);

  spsm_k<<<dim3(L), dim3(256), 0, stream>>>(sp, sps);

  gemm_k<64><<<dim3(L / 64, KS / 128), dim3(256), 0, stream>>>(xb, wqb, bq, q1, L, KS, D, 0, 1.f);
  gemm_k<64><<<dim3(L / 64, KS / 128), dim3(256), 0, stream>>>(xb, wkb, bk, k1, L, KS, D, 0, 1.f);
  gemm_k<64><<<dim3(L / 64, VS / 128), dim3(256), 0, stream>>>(xb, wvb, bv, v1, L, VS, D, 0, 1.f);
  gemm_k<64><<<dim3(L / 64, KS / 128), dim3(256), 0, stream>>>(q1, wqpb, bqp, qf, L, KS, KS, 0, 0.125f);
  gemm_k<64><<<dim3(L / 64, KS / 128), dim3(256), 0, stream>>>(k1, wkpb, bkp, kf, L, KS, KS, 0, 1.f);
  gemm_k<64><<<dim3(L / 64, VS / 128), dim3(256), 0, stream>>>(v1, wvpb, bvp, vf, L, VS, VS, 0, 1.f);

  vtr_k<<<dim3(L / 64, H), dim3(256), 0, stream>>>(vf, vT);

  attn_k<<<dim3(H, L / 64, 2), dim3(256), 0, stream>>>(qf, kf, vT, sps, opart, mlbuf);
  acomb_k<<<dim3(L), dim3(256), 0, stream>>>(opart, mlbuf, ob);

  gemm_k<64><<<dim3(L / 64, D / 128), dim3(256), 0, stream>>>(ob, wob, bo, opb, L, D, VS, 0, 1.f);
  ln_k<<<dim3(L), dim3(256), 0, stream>>>(x, opb, g1, be1, hb, hf);
  gemm_k<128><<<dim3(L / 128, HID / 128), dim3(256), 0, stream>>>(hb, w1b, b1, ffn1, L, HID, D, 1, 1.f);
  gemm_k<64><<<dim3(L / 64, D / 128), dim3(256), 0, stream>>>(ffn1, w2b, b2, fb, L, D, HID, 1, 1.f);
  ln_k<<<dim3(L), dim3(256), 0, stream>>>(hf, fb, g2, be2, (ushort*)nullptr, out);
}

// Round 3
// 227.748 us; speedup vs baseline: 1.9567x; 1.5027x over previous
//
#include <hip/hip_runtime.h>

typedef __attribute__((ext_vector_type(4))) float f32x4;
typedef __attribute__((ext_vector_type(8))) short s16x8;

static __device__ __forceinline__ ushort f2b(float f) {
  union { float f; unsigned u; } v; v.f = f;
  unsigned u = v.u;
  unsigned r = (u + 0x7fffu + ((u >> 16) & 1u)) >> 16;
  return (ushort)r;
}
static __device__ __forceinline__ float b2f(ushort h) {
  union { unsigned u; float f; } v; v.u = ((unsigned)h) << 16;
  return v.f;
}

static __device__ __forceinline__ void gload_lds16(const ushort* g, ushort* l) {
  __builtin_amdgcn_global_load_lds(
      (const __attribute__((address_space(1))) void*)g,
      (__attribute__((address_space(3))) void*)l, 16, 0, 0);
}

// ---------------- multi-region fp32 -> bf16 conversion (1 launch) ----------------
struct Cvt7 {
  const float* src[7];
  ushort* dst[7];
  int n[7];
};
__global__ __launch_bounds__(256) void cvt_multi_k(Cvt7 a) {
  int e = blockIdx.y;
  int i = (blockIdx.x * 256 + threadIdx.x) * 4;
  if (i >= a.n[e]) return;
  float4 v4 = *(const float4*)(a.src[e] + i);
  ushort4 o4; o4.x = f2b(v4.x); o4.y = f2b(v4.y); o4.z = f2b(v4.z); o4.w = f2b(v4.w);
  *(ushort4*)(a.dst[e] + i) = o4;
}

// ---------------- transpose+convert Wq/Wk/Wv -> bf16 [din][dout], q scaled 1/8 ----------------
__global__ __launch_bounds__(256) void wtr_k(const float* __restrict__ Wq,
                                             const float* __restrict__ Wk,
                                             const float* __restrict__ Wv,
                                             ushort* __restrict__ dst) {
  __shared__ float t[64][65];
  int z = blockIdx.z;
  const float* src = z == 0 ? Wq : (z == 1 ? Wk : Wv);
  float scale = z == 0 ? 0.125f : 1.f;
  int r0 = blockIdx.x * 64, c0 = blockIdx.y * 64;
  int lr = threadIdx.x >> 2, lc4 = (threadIdx.x & 3) * 16;
#pragma unroll
  for (int j = 0; j < 4; ++j)
    *(float4*)&t[lr][lc4 + j * 4] = *(const float4*)(src + (size_t)(r0 + lr) * 1024 + c0 + lc4 + j * 4);
  __syncthreads();
  ushort tmp[16];
#pragma unroll
  for (int j = 0; j < 16; ++j) tmp[j] = f2b(t[lc4 + j][lr] * scale);
  ushort* d = dst + (size_t)z * 1048576 + (size_t)(c0 + lr) * 1024 + r0 + lc4;
  *(uint4*)d = *(uint4*)tmp;
  *(uint4*)(d + 8) = *(uint4*)(tmp + 8);
}

// ---------------- combined bias: b' = Wp @ b + bp (scaled for q) ----------------
__global__ __launch_bounds__(256) void bvec_k(
    const float* __restrict__ Wqp, const float* __restrict__ Wkp, const float* __restrict__ Wvp,
    const float* __restrict__ bq, const float* __restrict__ bqp,
    const float* __restrict__ bk, const float* __restrict__ bkp,
    const float* __restrict__ bv, const float* __restrict__ bvp,
    float* __restrict__ outb) {
  int r = blockIdx.x * 4 + (threadIdx.x >> 6);
  int lane = threadIdx.x & 63;
  int z = r >> 10, rr = r & 1023;
  const float* Wp = z == 0 ? Wqp : (z == 1 ? Wkp : Wvp);
  const float* bi = z == 0 ? bq : (z == 1 ? bk : bv);
  const float* bp = z == 0 ? bqp : (z == 1 ? bkp : bvp);
  float s = 0.f;
#pragma unroll
  for (int t = 0; t < 4; ++t) {
    float4 w = *(const float4*)(Wp + (size_t)rr * 1024 + lane * 16 + t * 4);
    float4 b = *(const float4*)(bi + lane * 16 + t * 4);
    s += w.x * b.x + w.y * b.y + w.z * b.z + w.w * b.w;
  }
#pragma unroll
  for (int m = 1; m < 64; m <<= 1) s += __shfl_xor(s, m);
  if (lane == 0) outb[r] = (s + bp[rr]) * (z == 0 ? 0.125f : 1.f);
}

// ---------------- row softmax of shortest_path, scaled 0.5, bf16 out ----------------
__global__ __launch_bounds__(256) void spsm_k(const float* __restrict__ sp,
                                              ushort* __restrict__ out) {
  const int Lc = 2048;
  int row = blockIdx.x;
  int tid = threadIdx.x;
  const float* r = sp + (size_t)row * Lc;
  float v[8];
  float mx = -1e30f;
#pragma unroll
  for (int j = 0; j < 8; ++j) { v[j] = r[tid + j * 256]; mx = fmaxf(mx, v[j]); }
#pragma unroll
  for (int m = 1; m < 64; m <<= 1) mx = fmaxf(mx, __shfl_xor(mx, m));
  __shared__ float redm[4], reds[4];
  if ((tid & 63) == 0) redm[tid >> 6] = mx;
  __syncthreads();
  mx = fmaxf(fmaxf(redm[0], redm[1]), fmaxf(redm[2], redm[3]));
  float s = 0.f;
#pragma unroll
  for (int j = 0; j < 8; ++j) { v[j] = __expf(v[j] - mx); s += v[j]; }
#pragma unroll
  for (int m = 1; m < 64; m <<= 1) s += __shfl_xor(s, m);
  if ((tid & 63) == 0) reds[tid >> 6] = s;
  __syncthreads();
  s = reds[0] + reds[1] + reds[2] + reds[3];
  float inv = 0.5f / s;
  ushort* o = out + (size_t)row * Lc;
#pragma unroll
  for (int j = 0; j < 8; ++j) o[tid + j * 256] = f2b(v[j] * inv);
}

// ---------------- V pre-transpose: qkv v-cols -> vT[16][64][2048] ----------------
__global__ __launch_bounds__(256) void vtr_k(const ushort* __restrict__ qkv,
                                             ushort* __restrict__ vT) {
  __shared__ ushort t[64][72];
  int tid = threadIdx.x;
  int r = tid >> 3, c8 = (tid & 7) * 8;
  int l0 = blockIdx.x * 64, h = blockIdx.y;
#pragma unroll
  for (int p = 0; p < 2; ++p)
    *(uint4*)&t[r + p * 32][c8] =
        *(const uint4*)(qkv + (size_t)(l0 + r + p * 32) * 3072 + 2048 + h * 64 + c8);
  __syncthreads();
#pragma unroll
  for (int p = 0; p < 2; ++p) {
    int d = r + p * 32;
    ushort tmp[8];
#pragma unroll
    for (int j = 0; j < 8; ++j) tmp[j] = t[c8 + j][d];
    *(uint4*)(vT + ((size_t)h * 64 + d) * 2048 + l0 + c8) = *(uint4*)tmp;
  }
}

// ---------------- bf16 GEMM (m97 structure), ZM: 0=plain 1=z-batched 2=split-K2 ----------------
template <int BM, int ZM>
__global__ __launch_bounds__(256, 2) void gemm_k(
    const ushort* __restrict__ A, const ushort* __restrict__ W,
    const float* __restrict__ bias, void* __restrict__ Cv,
    int M, int N, int K, int relu, float oscale) {
  constexpr int MT = BM / 32;
  __shared__ ushort As[BM][64];
  __shared__ ushort Bs[128][64];
  const int z = (ZM != 0) ? blockIdx.z : 0;
  if (ZM == 1) { A += (size_t)z * M * K; W += (size_t)z * N * K; }
  int kb0 = 0, kb1 = K;
  if (ZM == 2) { int kh = K >> 1; kb0 = z * kh; kb1 = kb0 + kh; }
  const int tid = threadIdx.x;
  const int lane = tid & 63;
  const int wave = tid >> 6;
  const int wm = (wave >> 1) * (BM / 2);
  const int wn = (wave & 1) * 64;
  const int bm = blockIdx.x * BM;
  const int bn = blockIdx.y * 128;
  const int cl = lane & 15, rg = lane >> 4;
  const int lrow = lane >> 3, lcol = (lane & 7) * 8;

  f32x4 acc[MT][4];
#pragma unroll
  for (int i = 0; i < MT; ++i)
#pragma unroll
    for (int j = 0; j < 4; ++j) acc[i][j] = (f32x4){0.f, 0.f, 0.f, 0.f};

  const ushort* gA = A + (size_t)(bm + wave * 8 + lrow) * K + lcol;
  const ushort* gB = W + (size_t)(bn + wave * 8 + lrow) * K + lcol;
  ushort* lA = &As[wave * 8][0];
  ushort* lB = &Bs[wave * 8][0];

  for (int k0 = kb0; k0 < kb1; k0 += 64) {
#pragma unroll
    for (int c = 0; c < MT; ++c)
      gload_lds16(gA + (size_t)(c * 32) * K + k0, lA + c * 2048);
#pragma unroll
    for (int c = 0; c < 4; ++c)
      gload_lds16(gB + (size_t)(c * 32) * K + k0, lB + c * 2048);
    __syncthreads();
    const int kbo = 8 * rg;
#pragma unroll
    for (int kk = 0; kk < 64; kk += 32) {
      s16x8 af[MT], bf[4];
#pragma unroll
      for (int mt = 0; mt < MT; ++mt)
        af[mt] = *(const s16x8*)&As[wm + mt * 16 + cl][kk + kbo];
#pragma unroll
      for (int nt = 0; nt < 4; ++nt)
        bf[nt] = *(const s16x8*)&Bs[wn + nt * 16 + cl][kk + kbo];
#pragma unroll
      for (int mt = 0; mt < MT; ++mt)
#pragma unroll
        for (int nt = 0; nt < 4; ++nt)
          acc[mt][nt] = __builtin_amdgcn_mfma_f32_16x16x32_bf16(af[mt], bf[nt], acc[mt][nt], 0, 0, 0);
    }
    __syncthreads();
  }

  if (ZM == 2) {
    float* Cf = (float*)Cv + (size_t)z * M * N;
#pragma unroll
    for (int nt = 0; nt < 4; ++nt) {
      int c = bn + wn + nt * 16 + cl;
#pragma unroll
      for (int mt = 0; mt < MT; ++mt)
#pragma unroll
        for (int i = 0; i < 4; ++i) {
          int r = bm + wm + mt * 16 + rg * 4 + i;
          Cf[(size_t)r * N + c] = acc[mt][nt][i];
        }
    }
  } else {
    ushort* Cu = (ushort*)Cv;
    if (ZM == 1) Cu += (size_t)z * M * N;
#pragma unroll
    for (int nt = 0; nt < 4; ++nt) {
      int c = bn + wn + nt * 16 + cl;
      float bv = bias ? bias[c] : 0.f;
#pragma unroll
      for (int mt = 0; mt < MT; ++mt) {
#pragma unroll
        for (int i = 0; i < 4; ++i) {
          int r = bm + wm + mt * 16 + rg * 4 + i;
          float v = (acc[mt][nt][i] + bv) * oscale;
          if (relu) v = fmaxf(v, 0.f);
          Cu[(size_t)r * N + c] = f2b(v);
        }
      }
    }
  }
}

// ---------------- split-K combine: out = act(p0+p1+bias) ----------------
__global__ __launch_bounds__(256) void comb2_k(const float* __restrict__ p,
                                               const float* __restrict__ bias,
                                               ushort* __restrict__ out, int relu) {
  const int MN = 2048 * 1024;
  int i = (blockIdx.x * 256 + threadIdx.x) * 4;
  float4 a = *(const float4*)(p + i);
  float4 b = *(const float4*)(p + MN + i);
  float4 bb = *(const float4*)(bias + (i & 1023));
  float v0 = a.x + b.x + bb.x, v1 = a.y + b.y + bb.y;
  float v2 = a.z + b.z + bb.z, v3 = a.w + b.w + bb.w;
  if (relu) {
    v0 = fmaxf(v0, 0.f); v1 = fmaxf(v1, 0.f);
    v2 = fmaxf(v2, 0.f); v3 = fmaxf(v3, 0.f);
  }
  ushort4 o; o.x = f2b(v0); o.y = f2b(v1); o.z = f2b(v2); o.w = f2b(v3);
  *(ushort4*)(out + i) = o;
}

// ---------------- flash attention: fixed-max softmax, KV-split=2 ----------------
__global__ __launch_bounds__(256, 2) void attn_k(
    const ushort* __restrict__ qkv, const ushort* __restrict__ vT,
    const ushort* __restrict__ biasb, ushort* __restrict__ opart,
    float* __restrict__ lbuf) {
  const int Lc = 2048;
  int h = blockIdx.x;
  int m0 = blockIdx.y * 64;
  int s = blockIdx.z;
  int nb = s * 1024, ne = nb + 1024;
  int tid = threadIdx.x, lane = tid & 63, wave = tid >> 6;

  __shared__ ushort Qs[64][72];
  __shared__ ushort Ks[64][72];
  __shared__ ushort Vs[64][72];
  __shared__ ushort Ps[4][16][72];

  int srow = tid >> 3, scol = (tid & 7) * 8;
#pragma unroll
  for (int p = 0; p < 2; ++p) {
    int r = srow + p * 32;
    *(uint4*)&Qs[r][scol] = *(const uint4*)(qkv + (size_t)(m0 + r) * 3072 + h * 64 + scol);
  }

  f32x4 oacc[4];
#pragma unroll
  for (int i = 0; i < 4; ++i) oacc[i] = (f32x4){0.f, 0.f, 0.f, 0.f};
  float lacc[4] = {0.f, 0.f, 0.f, 0.f};

  const int rg = lane >> 4, cl = lane & 15;
  const int kb = 8 * rg;

  for (int n0 = nb; n0 < ne; n0 += 64) {
    __syncthreads();
#pragma unroll
    for (int p = 0; p < 2; ++p) {
      int r = srow + p * 32;
      *(uint4*)&Ks[r][scol] = *(const uint4*)(qkv + (size_t)(n0 + r) * 3072 + 1024 + h * 64 + scol);
      *(uint4*)&Vs[r][scol] = *(const uint4*)(vT + ((size_t)h * 64 + r) * 2048 + n0 + scol);
    }
    __syncthreads();

    // seed scores with bias - 8 (fixed softmax max); q carries 1/8 scale already
    f32x4 sacc[4];
#pragma unroll
    for (int nt = 0; nt < 4; ++nt)
#pragma unroll
      for (int i = 0; i < 4; ++i)
        sacc[nt][i] =
            b2f(biasb[(size_t)(m0 + wave * 16 + rg * 4 + i) * Lc + n0 + nt * 16 + cl]) - 8.f;

#pragma unroll
    for (int kk = 0; kk < 64; kk += 32) {
      s16x8 a = *(const s16x8*)&Qs[wave * 16 + cl][kk + kb];
#pragma unroll
      for (int nt = 0; nt < 4; ++nt) {
        s16x8 b = *(const s16x8*)&Ks[nt * 16 + cl][kk + kb];
        sacc[nt] = __builtin_amdgcn_mfma_f32_16x16x32_bf16(a, b, sacc[nt], 0, 0, 0);
      }
    }
#pragma unroll
    for (int i = 0; i < 4; ++i) {
#pragma unroll
      for (int nt = 0; nt < 4; ++nt) {
        float pv = __expf(sacc[nt][i]);
        sacc[nt][i] = pv;
        lacc[i] += pv;
      }
    }
#pragma unroll
    for (int nt = 0; nt < 4; ++nt)
#pragma unroll
      for (int i = 0; i < 4; ++i)
        Ps[wave][rg * 4 + i][nt * 16 + cl] = f2b(sacc[nt][i]);
#pragma unroll
    for (int kk = 0; kk < 64; kk += 32) {
      s16x8 a = *(const s16x8*)&Ps[wave][cl][kk + kb];
#pragma unroll
      for (int nt = 0; nt < 4; ++nt) {
        s16x8 b = *(const s16x8*)&Vs[nt * 16 + cl][kk + kb];
        oacc[nt] = __builtin_amdgcn_mfma_f32_16x16x32_bf16(a, b, oacc[nt], 0, 0, 0);
      }
    }
  }
#pragma unroll
  for (int nt = 0; nt < 4; ++nt) {
#pragma unroll
    for (int i = 0; i < 4; ++i) {
      int r = m0 + wave * 16 + rg * 4 + i;
      opart[((size_t)s * Lc + r) * 1024 + h * 64 + nt * 16 + cl] = f2b(oacc[nt][i]);
    }
  }
#pragma unroll
  for (int i = 0; i < 4; ++i) {
    float l = lacc[i];
#pragma unroll
    for (int m = 1; m < 16; m <<= 1) l += __shfl_xor(l, m);
    if (cl == 0) {
      int r = m0 + wave * 16 + rg * 4 + i;
      lbuf[(size_t)(s * 16 + h) * Lc + r] = l;
    }
  }
}

// ---------------- combine KV-splits: O = (O0+O1)/(l0+l1) ----------------
__global__ __launch_bounds__(256) void acomb_k(const ushort* __restrict__ op,
                                               const float* __restrict__ lbuf,
                                               ushort* __restrict__ ob) {
  const int Lc = 2048;
  int qrow = blockIdx.x;
  int tid = threadIdx.x;
  int c = tid * 4;
  int h = c >> 6;
  float l0 = lbuf[(size_t)h * Lc + qrow];
  float l1 = lbuf[(size_t)(16 + h) * Lc + qrow];
  float inv = 1.f / (l0 + l1);
  ushort4 a = *(const ushort4*)(op + (size_t)qrow * 1024 + c);
  ushort4 b = *(const ushort4*)(op + ((size_t)Lc + qrow) * 1024 + c);
  ushort4 o;
  o.x = f2b((b2f(a.x) + b2f(b.x)) * inv);
  o.y = f2b((b2f(a.y) + b2f(b.y)) * inv);
  o.z = f2b((b2f(a.z) + b2f(b.z)) * inv);
  o.w = f2b((b2f(a.w) + b2f(b.w)) * inv);
  *(ushort4*)(ob + (size_t)qrow * 1024 + c) = o;
}

// ---------------- residual + LayerNorm ----------------
__global__ __launch_bounds__(256) void ln_k(const float* __restrict__ base,
                                            const ushort* __restrict__ add,
                                            const float* __restrict__ g,
                                            const float* __restrict__ be,
                                            ushort* __restrict__ outb,
                                            float* __restrict__ outf) {
  const int Dc = 1024;
  int row = blockIdx.x;
  int tid = threadIdx.x;
  float4 bx = *(const float4*)(base + (size_t)row * Dc + tid * 4);
  ushort4 ax = *(const ushort4*)(add + (size_t)row * Dc + tid * 4);
  float v0 = bx.x + b2f(ax.x), v1 = bx.y + b2f(ax.y);
  float v2 = bx.z + b2f(ax.z), v3 = bx.w + b2f(ax.w);
  float s = v0 + v1 + v2 + v3;
  __shared__ float red[4];
#pragma unroll
  for (int m = 1; m < 64; m <<= 1) s += __shfl_xor(s, m);
  if ((tid & 63) == 0) red[tid >> 6] = s;
  __syncthreads();
  s = red[0] + red[1] + red[2] + red[3];
  float mu = s * (1.f / Dc);
  float d0 = v0 - mu, d1 = v1 - mu, d2 = v2 - mu, d3 = v3 - mu;
  float ss = d0 * d0 + d1 * d1 + d2 * d2 + d3 * d3;
  __syncthreads();
#pragma unroll
  for (int m = 1; m < 64; m <<= 1) ss += __shfl_xor(ss, m);
  if ((tid & 63) == 0) red[tid >> 6] = ss;
  __syncthreads();
  ss = red[0] + red[1] + red[2] + red[3];
  float rs = rsqrtf(ss * (1.f / Dc) + 1e-5f);
  int c = tid * 4;
  float4 gv = *(const float4*)(g + c);
  float4 bev = *(const float4*)(be + c);
  float y0 = d0 * rs * gv.x + bev.x;
  float y1 = d1 * rs * gv.y + bev.y;
  float y2 = d2 * rs * gv.z + bev.z;
  float y3 = d3 * rs * gv.w + bev.w;
  size_t o = (size_t)row * Dc + c;
  if (outb) {
    ushort4 ob4; ob4.x = f2b(y0); ob4.y = f2b(y1); ob4.z = f2b(y2); ob4.w = f2b(y3);
    *(ushort4*)(outb + o) = ob4;
  }
  if (outf) {
    float4 of4; of4.x = y0; of4.y = y1; of4.z = y2; of4.w = y3;
    *(float4*)(outf + o) = of4;
  }
}

extern "C" void kernel_launch(void* const* d_in, const int* in_sizes, int n_in,
                              void* d_out, int out_size, void* d_ws, size_t ws_size,
                              hipStream_t stream) {
  const int L = 2048, D = 1024, H = 16, HID = 4096;
  const float* x   = (const float*)d_in[0];
  const float* sp  = (const float*)d_in[1];
  const float* Wq  = (const float*)d_in[2];  const float* bq  = (const float*)d_in[3];
  const float* Wk  = (const float*)d_in[4];  const float* bk  = (const float*)d_in[5];
  const float* Wv  = (const float*)d_in[6];  const float* bv  = (const float*)d_in[7];
  const float* Wqp = (const float*)d_in[8];  const float* bqp = (const float*)d_in[9];
  const float* Wkp = (const float*)d_in[10]; const float* bkp = (const float*)d_in[11];
  const float* Wvp = (const float*)d_in[12]; const float* bvp = (const float*)d_in[13];
  const float* Wo  = (const float*)d_in[14]; const float* bo  = (const float*)d_in[15];
  const float* W1  = (const float*)d_in[16]; const float* b1  = (const float*)d_in[17];
  const float* W2  = (const float*)d_in[18]; const float* b2  = (const float*)d_in[19];
  const float* g1  = (const float*)d_in[20]; const float* be1 = (const float*)d_in[21];
  const float* g2  = (const float*)d_in[22]; const float* be2 = (const float*)d_in[23];
  float* out = (float*)d_out;

  size_t off = 0;
  char* base = (char*)d_ws;
  auto alloc = [&](size_t b) {
    char* p = base + off;
    off += (b + 255) & ~(size_t)255;
    return p;
  };
  ushort* xb    = (ushort*)alloc((size_t)L * D * 2);
  ushort* wqpb  = (ushort*)alloc((size_t)D * D * 2);   // these three contiguous (z-batch)
  ushort* wkpb  = (ushort*)alloc((size_t)D * D * 2);
  ushort* wvpb  = (ushort*)alloc((size_t)D * D * 2);
  // region R1: wqT(6MB) + wfused(6MB) + qkv(12MB) = 24MB, later reused by ffn1 (16MB)
  ushort* wqTb  = (ushort*)alloc((size_t)3 * D * D * 2);
  ushort* wfused= (ushort*)alloc((size_t)3 * D * D * 2);
  ushort* qkv   = (ushort*)alloc((size_t)L * 3072 * 2);
  float*  bfused= (float*)alloc((size_t)3072 * 4);
  ushort* wob   = (ushort*)alloc((size_t)D * D * 2);
  ushort* w1b   = (ushort*)alloc((size_t)HID * D * 2);
  ushort* w2b   = (ushort*)alloc((size_t)D * HID * 2);
  // region R2: spsb(8MB) + opart(8MB) = 16MB, later reused by split-K partials
  ushort* spsb  = (ushort*)alloc((size_t)L * L * 2);
  ushort* opart = (ushort*)alloc((size_t)2 * L * 1024 * 2);
  ushort* vT    = (ushort*)alloc((size_t)H * 64 * L * 2);   // later reused by opb
  float*  lbuf  = (float*)alloc((size_t)2 * H * L * 4);
  ushort* ob    = (ushort*)alloc((size_t)L * 1024 * 2);     // later reused by fb
  ushort* hb    = (ushort*)alloc((size_t)L * D * 2);
  float*  hf    = (float*)alloc((size_t)L * D * 4);

  ushort* ffn1  = wqTb;          // R1 reuse (16MB < 24MB)
  float*  parts = (float*)spsb;  // R2 reuse (16MB)
  ushort* opb   = vT;            // 4MB reuse
  ushort* fb    = ob;            // 4MB reuse

  // 1. all fp32->bf16 conversions in one launch
  Cvt7 ca;
  ca.src[0] = x;   ca.dst[0] = xb;   ca.n[0] = L * D;
  ca.src[1] = Wqp; ca.dst[1] = wqpb; ca.n[1] = D * D;
  ca.src[2] = Wkp; ca.dst[2] = wkpb; ca.n[2] = D * D;
  ca.src[3] = Wvp; ca.dst[3] = wvpb; ca.n[3] = D * D;
  ca.src[4] = Wo;  ca.dst[4] = wob;  ca.n[4] = D * D;
  ca.src[5] = W1;  ca.dst[5] = w1b;  ca.n[5] = HID * D;
  ca.src[6] = W2;  ca.dst[6] = w2b;  ca.n[6] = D * HID;
  cvt_multi_k<<<dim3(4096, 7), dim3(256), 0, stream>>>(ca);

  // 2. transpose-convert Wq/Wk/Wv (q scaled 1/8)
  wtr_k<<<dim3(16, 16, 3), dim3(256), 0, stream>>>(Wq, Wk, Wv, wqTb);
  // 3. combined biases
  bvec_k<<<dim3(768), dim3(256), 0, stream>>>(Wqp, Wkp, Wvp, bq, bqp, bk, bkp, bv, bvp, bfused);
  // 4. sp softmax (bf16)
  spsm_k<<<dim3(L), dim3(256), 0, stream>>>(sp, spsb);

  // 5. weight-combine GEMMs: W' = Wp @ Worig  (z-batched over q/k/v)
  gemm_k<64, 1><<<dim3(16, 8, 3), dim3(256), 0, stream>>>(
      wqpb, wqTb, (const float*)nullptr, wfused, D, D, D, 0, 1.f);
  // 6. fused QKV projection
  gemm_k<64, 0><<<dim3(32, 24), dim3(256), 0, stream>>>(
      xb, wfused, bfused, qkv, L, 3072, D, 0, 1.f);

  // 7. V transpose
  vtr_k<<<dim3(L / 64, H), dim3(256), 0, stream>>>(qkv, vT);
  // 8. attention
  attn_k<<<dim3(H, L / 64, 2), dim3(256), 0, stream>>>(qkv, vT, spsb, opart, lbuf);
  // 9. combine splits
  acomb_k<<<dim3(L), dim3(256), 0, stream>>>(opart, lbuf, ob);

  // 10-11. output projection (split-K2)
  gemm_k<64, 2><<<dim3(32, 8, 2), dim3(256), 0, stream>>>(
      ob, wob, (const float*)nullptr, parts, L, D, D, 0, 1.f);
  comb2_k<<<dim3(2048), dim3(256), 0, stream>>>(parts, bo, opb, 0);
  // 12. residual + LN1
  ln_k<<<dim3(L), dim3(256), 0, stream>>>(x, opb, g1, be1, hb, hf);
  // 13. FFN1 (relu)
  gemm_k<128, 0><<<dim3(16, 32), dim3(256), 0, stream>>>(
      hb, w1b, b1, ffn1, L, HID, D, 1, 1.f);
  // 14-15. FFN2 (split-K2, relu in combine)
  gemm_k<64, 2><<<dim3(32, 8, 2), dim3(256), 0, stream>>>(
      ffn1, w2b, (const float*)nullptr, parts, L, D, HID, 0, 1.f);
  comb2_k<<<dim3(2048), dim3(256), 0, stream>>>(parts, b2, fb, 1);
  // 16. residual + LN2 -> fp32 out
  ln_k<<<dim3(L), dim3(256), 0, stream>>>(hf, fb, g2, be2, (ushort*)nullptr, out);
}